// Round 7
// baseline (232.967 us; speedup 1.0000x reference)
//
#include <hip/hip_runtime.h>
#include <math.h>

#define N_NODES 5000
#define N_EDGES 50000
#define NPAD 5008                 // 313 * 16 (GEMM M padding)
#define KJ 4160                   // 65*64: k in 0..63 from t, slot 64 = ones (b2 fold)

typedef _Float16 f16x8 __attribute__((ext_vector_type(8)));
typedef float    f32x4 __attribute__((ext_vector_type(4)));

static __device__ __forceinline__ f32x4 mfma16f(f16x8 a, f16x8 b, f32x4 c) {
    return __builtin_amdgcn_mfma_f32_16x16x32_f16(a, b, c, 0, 0, 0);
}

// ---------------- prep: WrT fp16 + GRU weight transposes + zero cnt --------
// WrT[i][kj], kj=k*64+j: k<64 -> W2[k*4096+i*64+j]; k==64 -> b2[i*64+j]
__global__ void prep_kernel(const float* __restrict__ W2, const float* __restrict__ b2,
                            const float* __restrict__ Wih, const float* __restrict__ Whh,
                            _Float16* __restrict__ WrT, float* __restrict__ WihT,
                            float* __restrict__ WhhT, int* __restrict__ cnt) {
    int g = blockIdx.x * 256 + threadIdx.x;
    if (g < 266240) {
        int i = g / KJ, kj = g - i * KJ;
        int k = kj >> 6, j = kj & 63;
        float x = (k < 64) ? W2[k * 4096 + i * 64 + j] : b2[i * 64 + j];
        WrT[g] = (_Float16)x;
        return;
    }
    g -= 266240;
    if (g < 24576) {                      // GRU weight transposes WT[j][row]
        int which = g >= 12288;
        int tt = which ? g - 12288 : g;
        int row = tt >> 6, j = tt & 63;
        (which ? WhhT : WihT)[j * 192 + row] = (which ? Whh : Wih)[tt];
        return;
    }
    g -= 24576;
    if (g < N_NODES) cnt[g] = 0;
}

// ---------------- counting sort of edges by TGT ----------------------------
__global__ void hist_kernel(const int* __restrict__ ei, int* __restrict__ cnt) {
    int e = blockIdx.x * 256 + threadIdx.x;
    if (e < N_EDGES) atomicAdd(&cnt[ei[N_EDGES + e]], 1);
}

__global__ __launch_bounds__(1024) void scan_kernel(const int* __restrict__ cnt,
                                                    int* __restrict__ off,
                                                    int* __restrict__ cur) {
    __shared__ int s[1024];
    int tid = threadIdx.x;
    int base = tid * 5;                           // 1024*5 = 5120 >= 5000
    int loc[5]; int sum = 0;
#pragma unroll
    for (int q = 0; q < 5; ++q) {
        int v = (base + q < N_NODES) ? cnt[base + q] : 0;
        loc[q] = sum; sum += v;
    }
    s[tid] = sum; __syncthreads();
    for (int d = 1; d < 1024; d <<= 1) {
        int v = (tid >= d) ? s[tid - d] : 0;
        __syncthreads();
        s[tid] += v;
        __syncthreads();
    }
    int excl = (tid > 0) ? s[tid - 1] : 0;
#pragma unroll
    for (int q = 0; q < 5; ++q)
        if (base + q < N_NODES) { off[base + q] = excl + loc[q]; cur[base + q] = excl + loc[q]; }
    if (tid == 1023) off[N_NODES] = excl + sum;
}

__global__ void scatter_kernel(const int* __restrict__ ei, int* __restrict__ cur,
                               int* __restrict__ srcp, int* __restrict__ eidp) {
    int e = blockIdx.x * 256 + threadIdx.x;
    if (e < N_EDGES) {
        int q = atomicAdd(&cur[ei[N_EDGES + e]], 1);
        srcp[q] = ei[e];
        eidp[q] = e;
    }
}

// ---------------- t[q] = relu(ef[eidp[q]] @ W1 + b1) (tgt-sorted order) ----
__global__ void edge_mlp1_kernel(const int* __restrict__ eidp,
                                 const float* __restrict__ ef,
                                 const float* __restrict__ W1,
                                 const float* __restrict__ b1,
                                 float* __restrict__ t) {
    int gid = blockIdx.x * 256 + threadIdx.x;   // exact: 12500*256 = E*64
    int q = gid >> 6, i = gid & 63;
    int e = eidp[q];
    float acc = b1[i];
#pragma unroll
    for (int k = 0; k < 16; ++k)
        acc += ef[e * 16 + k] * W1[k * 64 + i];
    t[gid] = fmaxf(acc, 0.f);
}

// ---------------- H[v][k*64+j] = sum_{e->v} t[e,k]*h[src,j]; slot 64 = sum h
// wave per target v; lane = j; 65 fp32 accumulators; fp16 store.
__global__ __launch_bounds__(256) void hbuild_kernel(const int* __restrict__ toff,
                                                     const int* __restrict__ srcp,
                                                     const float* __restrict__ t,
                                                     const float* __restrict__ h,
                                                     _Float16* __restrict__ H) {
    int wave = threadIdx.x >> 6, lane = threadIdx.x & 63;
    int v = blockIdx.x * 4 + wave;                // grid 1252 -> 5008 (pad rows zero)
    float acc[65];
#pragma unroll
    for (int k = 0; k < 65; ++k) acc[k] = 0.f;
    if (v < N_NODES) {
        int s0 = toff[v], s1 = toff[v + 1];
        for (int q = s0; q < s1; ++q) {
            int s = srcp[q];                      // contiguous list
            float hv = h[s * 64 + lane];          // h is 1.25 MB -> L2-hot
            const float4* tq = (const float4*)(t + (size_t)q * 64);
#pragma unroll
            for (int kb = 0; kb < 16; ++kb) {
                float4 tv = tq[kb];               // broadcast load
                acc[kb * 4 + 0] += tv.x * hv;
                acc[kb * 4 + 1] += tv.y * hv;
                acc[kb * 4 + 2] += tv.z * hv;
                acc[kb * 4 + 3] += tv.w * hv;
            }
            acc[64] += hv;                        // ones-slot (b2*h term)
        }
    }
    _Float16* Hv = H + (size_t)v * KJ + lane;
#pragma unroll
    for (int k = 0; k < 65; ++k) Hv[k * 64] = (_Float16)acc[k];
}

// ---------------- m = H @ WrT^T (fp16 MFMA, K=4160) + fused GRU ------------
// block = 512 thr / 8 waves, one M-tile of 16 nodes, K split 8 ways,
// LDS reduce, GRU epilogue. 313 blocks.
__global__ __launch_bounds__(512) void gemm_gru_kernel(const _Float16* __restrict__ H,
                                                       const _Float16* __restrict__ WrT,
                                                       const float* __restrict__ h,
                                                       const float* __restrict__ WihT,
                                                       const float* __restrict__ WhhT,
                                                       const float* __restrict__ bih,
                                                       const float* __restrict__ bhh,
                                                       float* __restrict__ out) {
    __shared__ float lm[16 * 64];
    int tid = threadIdx.x;
    int w = tid >> 6, lane = tid & 63;
    int m0 = blockIdx.x * 16;                     // 313*16 = 5008 = NPAD
    int lo = lane & 15, q8 = (lane >> 4) * 8;
    // K partition: 130 k-steps of 32; waves 0,1 take 17, others 16
    int ks0 = w * 16 + ((w < 2) ? w : 2);
    int nsteps = 16 + ((w < 2) ? 1 : 0);
    const _Float16* Ap = H + (size_t)(m0 + lo) * KJ + q8;
    const _Float16* B0 = WrT + (size_t)(lo) * KJ + q8;
    const _Float16* B1 = WrT + (size_t)(16 + lo) * KJ + q8;
    const _Float16* B2 = WrT + (size_t)(32 + lo) * KJ + q8;
    const _Float16* B3 = WrT + (size_t)(48 + lo) * KJ + q8;
    f32x4 acc0 = {0.f, 0.f, 0.f, 0.f}, acc1 = acc0, acc2 = acc0, acc3 = acc0;
    for (int s = 0; s < nsteps; ++s) {
        int off = (ks0 + s) * 32;
        f16x8 a = *(const f16x8*)(Ap + off);
        acc0 = mfma16f(a, *(const f16x8*)(B0 + off), acc0);
        acc1 = mfma16f(a, *(const f16x8*)(B1 + off), acc1);
        acc2 = mfma16f(a, *(const f16x8*)(B2 + off), acc2);
        acc3 = mfma16f(a, *(const f16x8*)(B3 + off), acc3);
    }
    lm[tid] = 0.f; lm[tid + 512] = 0.f;
    __syncthreads();
    int row4 = (lane >> 4) * 4;
#pragma unroll
    for (int g = 0; g < 4; ++g) {                 // D: col=lane&15, row=quad*4+g
        atomicAdd(&lm[(row4 + g) * 64 + lo],       acc0[g]);
        atomicAdd(&lm[(row4 + g) * 64 + 16 + lo],  acc1[g]);
        atomicAdd(&lm[(row4 + g) * 64 + 32 + lo],  acc2[g]);
        atomicAdd(&lm[(row4 + g) * 64 + 48 + lo],  acc3[g]);
    }
    __syncthreads();
    // GRU epilogue: wave w handles nodes m0+2w, m0+2w+1; lane = output i
    int i = lane;
#pragma unroll
    for (int u = 0; u < 2; ++u) {
        int nl = w * 2 + u;
        int n = m0 + nl;
        if (n >= N_NODES) continue;
        float ir = bih[i], iz = bih[64 + i], inn = bih[128 + i];
        float hr = bhh[i], hz = bhh[64 + i], hn = bhh[128 + i];
        const float* mrow = lm + nl * 64;
        const float4* hnp = (const float4*)(h + (size_t)n * 64);
#pragma unroll 4
        for (int qb = 0; qb < 16; ++qb) {
            float4 hv = hnp[qb];
#pragma unroll
            for (int u2 = 0; u2 < 4; ++u2) {
                int j = qb * 4 + u2;
                float mv = mrow[j];               // LDS broadcast
                float hvx = u2 == 0 ? hv.x : u2 == 1 ? hv.y : u2 == 2 ? hv.z : hv.w;
                const float* wi = WihT + j * 192; // lane-coalesced rows
                const float* wh = WhhT + j * 192;
                ir  += mv  * wi[i];
                iz  += mv  * wi[64 + i];
                inn += mv  * wi[128 + i];
                hr  += hvx * wh[i];
                hz  += hvx * wh[64 + i];
                hn  += hvx * wh[128 + i];
            }
        }
        float hval = h[(size_t)n * 64 + i];
        float r = 1.f / (1.f + expf(-(ir + hr)));
        float z = 1.f / (1.f + expf(-(iz + hz)));
        float nn = tanhf(inn + r * hn);
        out[n * 64 + i] = (1.f - z) * nn + z * hval;
    }
}

extern "C" void kernel_launch(void* const* d_in, const int* in_sizes, int n_in,
                              void* d_out, int out_size, void* d_ws, size_t ws_size,
                              hipStream_t stream) {
    const float* h   = (const float*)d_in[0];
    const int*   ei  = (const int*)d_in[1];    // [2, E]: row0 = src, row1 = tgt
    const float* ef  = (const float*)d_in[2];
    const float* W1  = (const float*)d_in[3];
    const float* b1  = (const float*)d_in[4];
    const float* W2  = (const float*)d_in[5];
    const float* b2  = (const float*)d_in[6];
    const float* Wih = (const float*)d_in[7];
    const float* Whh = (const float*)d_in[8];
    const float* bih = (const float*)d_in[9];
    const float* bhh = (const float*)d_in[10];
    float* out = (float*)d_out;

    // ws layout (~56 MB): t | H | WrT | WihT | WhhT | cnt | toff | cur | srcp | eidp
    float*    t    = (float*)d_ws;                         // 3,200,000 f32
    _Float16* H    = (_Float16*)(t + 3200000);             // NPAD*KJ f16 (41.7 MB)
    _Float16* WrT  = H + (size_t)NPAD * KJ;                // 266,240 f16
    float*    WihT = (float*)(WrT + 266240);               // 12,288
    float*    WhhT = WihT + 12288;                         // 12,288
    int*      cnt  = (int*)(WhhT + 12288);                 // 5000
    int*      toff = cnt + N_NODES;                        // 5001
    int*      cur  = toff + N_NODES + 1;                   // 5000
    int*      srcp = cur + N_NODES;                        // 50000
    int*      eidp = srcp + N_EDGES;                       // 50000

    prep_kernel<<<1157, 256, 0, stream>>>(W2, b2, Wih, Whh, WrT, WihT, WhhT, cnt);
    hist_kernel<<<196, 256, 0, stream>>>(ei, cnt);
    scan_kernel<<<1, 1024, 0, stream>>>(cnt, toff, cur);
    scatter_kernel<<<196, 256, 0, stream>>>(ei, cur, srcp, eidp);
    edge_mlp1_kernel<<<12500, 256, 0, stream>>>(eidp, ef, W1, b1, t);
    hbuild_kernel<<<1252, 256, 0, stream>>>(toff, srcp, t, h, H);
    gemm_gru_kernel<<<313, 512, 0, stream>>>(H, WrT, h, WihT, WhhT, bih, bhh, out);
}